// Round 1
// baseline (1150.711 us; speedup 1.0000x reference)
//
#include <hip/hip_runtime.h>

typedef unsigned short u16;
typedef short s16x8 __attribute__((ext_vector_type(8)));
typedef float f32x4 __attribute__((ext_vector_type(4)));

#define USE_GLL 1

__device__ __forceinline__ u16 f2bf(float f) {
  union { float f; unsigned u; } x; x.f = f;
  unsigned r = (x.u + 0x7fffu + ((x.u >> 16) & 1u)) >> 16;
  return (u16)r;
}
__device__ __forceinline__ float bf2f(u16 u) {
  union { unsigned u; float f; } x; x.u = ((unsigned)u) << 16;
  return x.f;
}

#if USE_GLL
__device__ __forceinline__ void load_lds16(const u16* g, void* lds) {
  __builtin_amdgcn_global_load_lds(
      (const __attribute__((address_space(1))) unsigned int*)g,
      (__attribute__((address_space(3))) unsigned int*)lds, 16, 0, 0);
}
#endif

// ---------------- prep kernels ----------------

__global__ __launch_bounds__(256) void cast_bf16_kernel(const float* __restrict__ src,
                                                        u16* __restrict__ dst, int n4) {
  int id = blockIdx.x * 256 + threadIdx.x;
  if (id >= n4) return;
  float4 v = ((const float4*)src)[id];
  u16* d = dst + (size_t)id * 4;
  d[0] = f2bf(v.x); d[1] = f2bf(v.y); d[2] = f2bf(v.z); d[3] = f2bf(v.w);
}

__global__ __launch_bounds__(256) void pack_qkv_w_kernel(const float* __restrict__ wq,
                                                         const float* __restrict__ wk,
                                                         const float* __restrict__ wv,
                                                         u16* __restrict__ dst) {
  int id = blockIdx.x * 256 + threadIdx.x;   // over 3072*512 float4 groups
  if (id >= 3072 * 512) return;
  int row = id >> 9;
  int c4 = (id & 511) * 4;
  const float* src; int srow;
  if (row < 2048)      { src = wq; srow = row; }
  else if (row < 2560) { src = wk; srow = row - 2048; }
  else                 { src = wv; srow = row - 2560; }
  float4 v = *(const float4*)&src[(size_t)srow * 2048 + c4];
  u16* d = dst + (size_t)row * 2048 + c4;
  d[0] = f2bf(v.x); d[1] = f2bf(v.y); d[2] = f2bf(v.z); d[3] = f2bf(v.w);
}

__global__ __launch_bounds__(256) void pack_bias_kernel(const float* __restrict__ bq,
                                                        const float* __restrict__ bk,
                                                        const float* __restrict__ bv,
                                                        float* __restrict__ dst) {
  int id = blockIdx.x * 256 + threadIdx.x;
  if (id >= 3072) return;
  float v;
  if (id < 2048)      v = bq[id];
  else if (id < 2560) v = bk[id - 2048];
  else                v = bv[id - 2560];
  dst[id] = v;
}

__global__ __launch_bounds__(256) void rope_table_kernel(float* __restrict__ cosb,
                                                         float* __restrict__ sinb) {
  int id = blockIdx.x * 256 + threadIdx.x;   // S*64 = 131072
  if (id >= 2048 * 64) return;
  int s = id >> 6, i = id & 63;
  float freq = powf(10000.0f, -(float)i / 64.0f);
  float ang = (float)s * freq;
  cosb[id] = cosf(ang);
  sinb[id] = sinf(ang);
}

// in-place RoPE on bf16 buffer laid out [rows][128], rows = NH*S
__global__ __launch_bounds__(256) void rope_kernel(u16* __restrict__ p,
                                                   const float* __restrict__ cosb,
                                                   const float* __restrict__ sinb,
                                                   int total) {
  int id = blockIdx.x * 256 + threadIdx.x;   // total = rows*64
  if (id >= total) return;
  int i = id & 63;
  int rs = id >> 6;
  int s = rs & 2047;                          // S = 2048
  size_t base = (size_t)rs * 128;
  float x1 = bf2f(p[base + i]);
  float x2 = bf2f(p[base + i + 64]);
  float c = cosb[s * 64 + i], sn = sinb[s * 64 + i];
  p[base + i]      = f2bf(x1 * c - x2 * sn);
  p[base + i + 64] = f2bf(x2 * c + x1 * sn);
}

// ---------------- bf16 MFMA GEMM: C[m,n] = sum_k A[m,k]*B[n,k] (+bias) ----------------
// mode 0: scatter to Q/K/V bf16 buffers (+bias). mode 1: plain f32 C.
__global__ __launch_bounds__(256) void gemm_bt_kernel(
    const u16* __restrict__ A, const u16* __restrict__ Bw,
    const float* __restrict__ bias,
    float* __restrict__ C, int ldc,
    u16* __restrict__ Qp, u16* __restrict__ Kp, u16* __restrict__ Vp,
    int M, int N, int K, int mode) {
  __shared__ u16 sA[128 * 32];
  __shared__ u16 sB[128 * 32];
  const int t = threadIdx.x;
  const int w = t >> 6, l = t & 63;
  const int wm = (w >> 1) * 64, wn = (w & 1) * 64;
  const int m0 = blockIdx.y * 128, n0 = blockIdx.x * 128;
  const int srow = t >> 2, scol = (t & 3) * 8;

  f32x4 acc[4][4];
#pragma unroll
  for (int i = 0; i < 4; ++i)
#pragma unroll
    for (int j = 0; j < 4; ++j)
#pragma unroll
      for (int r = 0; r < 4; ++r) acc[i][j][r] = 0.0f;

  const size_t arow0 = (size_t)(m0 + srow) * K;
  const size_t arow1 = (size_t)(m0 + 64 + srow) * K;
  const size_t brow0 = (size_t)(n0 + srow) * K;
  const size_t brow1 = (size_t)(n0 + 64 + srow) * K;
#if USE_GLL
  char* ldsA = (char*)sA + (size_t)w * 1024;
  char* ldsB = (char*)sB + (size_t)w * 1024;
#endif

  for (int k0 = 0; k0 < K; k0 += 32) {
#if USE_GLL
    load_lds16(A + arow0 + k0 + scol, ldsA);
    load_lds16(A + arow1 + k0 + scol, ldsA + 4096);
    load_lds16(Bw + brow0 + k0 + scol, ldsB);
    load_lds16(Bw + brow1 + k0 + scol, ldsB + 4096);
#else
    {
      s16x8 a0 = *(const s16x8*)(A + arow0 + k0 + scol);
      s16x8 a1 = *(const s16x8*)(A + arow1 + k0 + scol);
      s16x8 b0 = *(const s16x8*)(Bw + brow0 + k0 + scol);
      s16x8 b1 = *(const s16x8*)(Bw + brow1 + k0 + scol);
      *(s16x8*)&sA[(size_t)srow * 32 + scol] = a0;
      *(s16x8*)&sA[(size_t)(64 + srow) * 32 + scol] = a1;
      *(s16x8*)&sB[(size_t)srow * 32 + scol] = b0;
      *(s16x8*)&sB[(size_t)(64 + srow) * 32 + scol] = b1;
    }
#endif
    __syncthreads();
    s16x8 af[4], bf[4];
#pragma unroll
    for (int m = 0; m < 4; ++m)
      af[m] = *(const s16x8*)&sA[(wm + m * 16 + (l & 15)) * 32 + (l >> 4) * 8];
#pragma unroll
    for (int n = 0; n < 4; ++n)
      bf[n] = *(const s16x8*)&sB[(wn + n * 16 + (l & 15)) * 32 + (l >> 4) * 8];
#pragma unroll
    for (int m = 0; m < 4; ++m)
#pragma unroll
      for (int n = 0; n < 4; ++n)
        acc[m][n] = __builtin_amdgcn_mfma_f32_16x16x32_bf16(af[m], bf[n], acc[m][n], 0, 0, 0);
    __syncthreads();
  }

#pragma unroll
  for (int m = 0; m < 4; ++m) {
#pragma unroll
    for (int n = 0; n < 4; ++n) {
#pragma unroll
      for (int r = 0; r < 4; ++r) {
        int row = m0 + wm + m * 16 + ((l >> 4) << 2) + r;
        int col = n0 + wn + n * 16 + (l & 15);
        float val = acc[m][n][r];
        if (mode == 0) {
          val += bias[col];
          int b = row >> 11, s = row & 2047;
          u16 bvv = f2bf(val);
          if (col < 2048) {
            int h = col >> 7, d = col & 127;
            Qp[(((size_t)(b * 16 + h)) * 2048 + s) * 128 + d] = bvv;
          } else if (col < 2560) {
            int cc = col - 2048; int kh = cc >> 7, d = cc & 127;
            Kp[(((size_t)(b * 4 + kh)) * 2048 + s) * 128 + d] = bvv;
          } else {
            int cc = col - 2560; int kh = cc >> 7, d = cc & 127;
            Vp[(((size_t)(b * 4 + kh)) * 2048 + s) * 128 + d] = bvv;
          }
        } else {
          C[(size_t)row * ldc + col] = val;
        }
      }
    }
  }
}

// ---------------- f32 flash attention (causal, GQA) ----------------
// Q: [B,16,S,128] bf16 (rope'd), K/V: [B,4,S,128] bf16 (K rope'd)
// O: [B,S,2048] bf16.  grid = (B*16, S/32), block = 256.
__global__ __launch_bounds__(256) void flash_kernel(const u16* __restrict__ Q,
                                                    const u16* __restrict__ Kb,
                                                    const u16* __restrict__ Vb,
                                                    u16* __restrict__ O) {
  const int S = 2048;
  __shared__ float sQ[32][128];
  __shared__ float sK[32][132];   // padded stride vs bank conflicts
  __shared__ float sV[32][128];
  __shared__ float sP[4][32][8];

  const int t = threadIdx.x, w = t >> 6, l = t & 63;
  const int bh = blockIdx.x, b = bh >> 4, h = bh & 15, kvh = h >> 2;
  const int q0 = blockIdx.y * 32;

  const u16* qbase = Q + (((size_t)(b * 16 + h)) * S + q0) * 128;
  const u16* kbase = Kb + ((size_t)(b * 4 + kvh)) * S * 128;
  const u16* vbase = Vb + ((size_t)(b * 4 + kvh)) * S * 128;

  // stage Q rows (32 x 128)
#pragma unroll
  for (int i = 0; i < 2; ++i) {
    int c = t + i * 256;                  // 512 chunks of 8
    int row = c >> 4, col8 = (c & 15) * 8;
    s16x8 v = *(const s16x8*)&qbase[(size_t)row * 128 + col8];
#pragma unroll
    for (int e = 0; e < 8; ++e) sQ[row][col8 + e] = bf2f((u16)v[e]);
  }

  float o2x[8], o2y[8], mrun[8], lrun[8];
#pragma unroll
  for (int r = 0; r < 8; ++r) { o2x[r] = 0.f; o2y[r] = 0.f; mrun[r] = -1e30f; lrun[r] = 0.f; }

  const int kv = l & 31, dbase = (l >> 5) * 64;
  const int nt = q0 / 32 + 1;
  for (int kt = 0; kt < nt; ++kt) {
    __syncthreads();   // Q staged (it=0); sK/sV free of prior readers (it>0)
#pragma unroll
    for (int i = 0; i < 2; ++i) {
      int c = t + i * 256;
      int row = c >> 4, col8 = (c & 15) * 8;
      s16x8 kk = *(const s16x8*)&kbase[((size_t)(kt * 32 + row)) * 128 + col8];
      s16x8 vv = *(const s16x8*)&vbase[((size_t)(kt * 32 + row)) * 128 + col8];
#pragma unroll
      for (int e = 0; e < 8; ++e) {
        sK[row][col8 + e] = bf2f((u16)kk[e]);
        sV[row][col8 + e] = bf2f((u16)vv[e]);
      }
    }
    __syncthreads();

    float s8[8];
#pragma unroll
    for (int r = 0; r < 8; ++r) s8[r] = 0.f;
#pragma unroll
    for (int d4 = 0; d4 < 16; ++d4) {
      float4 k4 = *(const float4*)&sK[kv][dbase + d4 * 4];
#pragma unroll
      for (int r = 0; r < 8; ++r) {
        float4 q4 = *(const float4*)&sQ[w * 8 + r][dbase + d4 * 4];
        s8[r] += q4.x * k4.x + q4.y * k4.y + q4.z * k4.z + q4.w * k4.w;
      }
    }
    const int jg = kt * 32 + kv;
    float p8[8];
#pragma unroll
    for (int r = 0; r < 8; ++r) {
      s8[r] += __shfl_xor(s8[r], 32);
      int qi = q0 + w * 8 + r;
      float sv = (jg <= qi) ? s8[r] * 0.08838834764831845f : -1e30f;
      float mt = sv;
#pragma unroll
      for (int off = 1; off < 32; off <<= 1) mt = fmaxf(mt, __shfl_xor(mt, off));
      float mnew = fmaxf(mrun[r], mt);
      float pp = __expf(sv - mnew);
      float corr = __expf(mrun[r] - mnew);
      float ps = pp;
#pragma unroll
      for (int off = 1; off < 32; off <<= 1) ps += __shfl_xor(ps, off);
      lrun[r] = lrun[r] * corr + ps;
      o2x[r] *= corr; o2y[r] *= corr;
      mrun[r] = mnew;
      p8[r] = pp;
    }
    if (l < 32) {
      float4 pa; pa.x = p8[0]; pa.y = p8[1]; pa.z = p8[2]; pa.w = p8[3];
      float4 pb; pb.x = p8[4]; pb.y = p8[5]; pb.z = p8[6]; pb.w = p8[7];
      *(float4*)&sP[w][l][0] = pa;
      *(float4*)&sP[w][l][4] = pb;
    }
    asm volatile("s_waitcnt lgkmcnt(0)" ::: "memory");
#pragma unroll 4
    for (int j = 0; j < 32; ++j) {
      float4 pa = *(const float4*)&sP[w][j][0];
      float4 pb = *(const float4*)&sP[w][j][4];
      float2 v2 = *(const float2*)&sV[j][l * 2];
      o2x[0] += pa.x * v2.x; o2y[0] += pa.x * v2.y;
      o2x[1] += pa.y * v2.x; o2y[1] += pa.y * v2.y;
      o2x[2] += pa.z * v2.x; o2y[2] += pa.z * v2.y;
      o2x[3] += pa.w * v2.x; o2y[3] += pa.w * v2.y;
      o2x[4] += pb.x * v2.x; o2y[4] += pb.x * v2.y;
      o2x[5] += pb.y * v2.x; o2y[5] += pb.y * v2.y;
      o2x[6] += pb.z * v2.x; o2y[6] += pb.z * v2.y;
      o2x[7] += pb.w * v2.x; o2y[7] += pb.w * v2.y;
    }
  }

#pragma unroll
  for (int r = 0; r < 8; ++r) {
    int qi = q0 + w * 8 + r;
    float inv = 1.0f / lrun[r];
    size_t base = ((size_t)b * S + qi) * 2048 + h * 128 + l * 2;
    O[base]     = f2bf(o2x[r] * inv);
    O[base + 1] = f2bf(o2y[r] * inv);
  }
}

// ---------------- launch ----------------

extern "C" void kernel_launch(void* const* d_in, const int* in_sizes, int n_in,
                              void* d_out, int out_size, void* d_ws, size_t ws_size,
                              hipStream_t stream) {
  const float* x  = (const float*)d_in[0];
  const float* wq = (const float*)d_in[1];
  const float* bq = (const float*)d_in[2];
  const float* wk = (const float*)d_in[3];
  const float* bk = (const float*)d_in[4];
  const float* wv = (const float*)d_in[5];
  const float* bv = (const float*)d_in[6];
  const float* wo = (const float*)d_in[7];
  float* out = (float*)d_out;

  char* ws = (char*)d_ws;
  u16* xb    = (u16*)ws;    ws += (size_t)4096 * 2048 * 2;
  u16* wqkv  = (u16*)ws;    ws += (size_t)3072 * 2048 * 2;
  float* bqkv = (float*)ws; ws += (size_t)3072 * 4;
  u16* wob   = (u16*)ws;    ws += (size_t)2048 * 2048 * 2;
  u16* Qb    = (u16*)ws;    ws += (size_t)32 * 2048 * 128 * 2;
  u16* Kbuf  = (u16*)ws;    ws += (size_t)8 * 2048 * 128 * 2;
  u16* Vbuf  = (u16*)ws;    ws += (size_t)8 * 2048 * 128 * 2;
  float* cosb = (float*)ws; ws += (size_t)2048 * 64 * 4;
  float* sinb = (float*)ws; ws += (size_t)2048 * 64 * 4;
  u16* att   = (u16*)ws;    ws += (size_t)4096 * 2048 * 2;

  cast_bf16_kernel<<<8192, 256, 0, stream>>>(x, xb, 4096 * 2048 / 4);
  pack_qkv_w_kernel<<<6144, 256, 0, stream>>>(wq, wk, wv, wqkv);
  pack_bias_kernel<<<12, 256, 0, stream>>>(bq, bk, bv, bqkv);
  cast_bf16_kernel<<<4096, 256, 0, stream>>>(wo, wob, 2048 * 2048 / 4);
  rope_table_kernel<<<512, 256, 0, stream>>>(cosb, sinb);

  gemm_bt_kernel<<<dim3(24, 32), 256, 0, stream>>>(xb, wqkv, bqkv, nullptr, 0,
                                                   Qb, Kbuf, Vbuf, 4096, 3072, 2048, 0);
  rope_kernel<<<16384, 256, 0, stream>>>(Qb, cosb, sinb, 32 * 2048 * 64);
  rope_kernel<<<4096, 256, 0, stream>>>(Kbuf, cosb, sinb, 8 * 2048 * 64);

  flash_kernel<<<dim3(32, 64), 256, 0, stream>>>(Qb, Kbuf, Vbuf, att);

  gemm_bt_kernel<<<dim3(16, 32), 256, 0, stream>>>(att, wob, nullptr, out, 2048,
                                                   nullptr, nullptr, nullptr, 4096, 2048, 2048, 1);
}

// Round 2
// 339.854 us; speedup vs baseline: 3.3859x; 3.3859x over previous
//
#include <hip/hip_runtime.h>

typedef unsigned short u16;
typedef short s16x8 __attribute__((ext_vector_type(8)));
typedef float f32x4 __attribute__((ext_vector_type(4)));

#define USE_GLL 1

__device__ __forceinline__ u16 f2bf(float f) {
  union { float f; unsigned u; } x; x.f = f;
  unsigned r = (x.u + 0x7fffu + ((x.u >> 16) & 1u)) >> 16;
  return (u16)r;
}
__device__ __forceinline__ float bf2f(u16 u) {
  union { unsigned u; float f; } x; x.u = ((unsigned)u) << 16;
  return x.f;
}

#if USE_GLL
__device__ __forceinline__ void load_lds16(const u16* g, void* lds) {
  __builtin_amdgcn_global_load_lds(
      (const __attribute__((address_space(1))) unsigned int*)g,
      (__attribute__((address_space(3))) unsigned int*)lds, 16, 0, 0);
}
#endif

// ---------------- prep kernels ----------------

__global__ __launch_bounds__(256) void cast_bf16_kernel(const float* __restrict__ src,
                                                        u16* __restrict__ dst, int n4) {
  int id = blockIdx.x * 256 + threadIdx.x;
  if (id >= n4) return;
  float4 v = ((const float4*)src)[id];
  u16* d = dst + (size_t)id * 4;
  d[0] = f2bf(v.x); d[1] = f2bf(v.y); d[2] = f2bf(v.z); d[3] = f2bf(v.w);
}

__global__ __launch_bounds__(256) void pack_qkv_w_kernel(const float* __restrict__ wq,
                                                         const float* __restrict__ wk,
                                                         const float* __restrict__ wv,
                                                         u16* __restrict__ dst) {
  int id = blockIdx.x * 256 + threadIdx.x;   // over 3072*512 float4 groups
  if (id >= 3072 * 512) return;
  int row = id >> 9;
  int c4 = (id & 511) * 4;
  const float* src; int srow;
  if (row < 2048)      { src = wq; srow = row; }
  else if (row < 2560) { src = wk; srow = row - 2048; }
  else                 { src = wv; srow = row - 2560; }
  float4 v = *(const float4*)&src[(size_t)srow * 2048 + c4];
  u16* d = dst + (size_t)row * 2048 + c4;
  d[0] = f2bf(v.x); d[1] = f2bf(v.y); d[2] = f2bf(v.z); d[3] = f2bf(v.w);
}

__global__ __launch_bounds__(256) void pack_bias_kernel(const float* __restrict__ bq,
                                                        const float* __restrict__ bk,
                                                        const float* __restrict__ bv,
                                                        float* __restrict__ dst) {
  int id = blockIdx.x * 256 + threadIdx.x;
  if (id >= 3072) return;
  float v;
  if (id < 2048)      v = bq[id];
  else if (id < 2560) v = bk[id - 2048];
  else                v = bv[id - 2560];
  dst[id] = v;
}

__global__ __launch_bounds__(256) void rope_table_kernel(float* __restrict__ cosb,
                                                         float* __restrict__ sinb) {
  int id = blockIdx.x * 256 + threadIdx.x;   // S*64 = 131072
  if (id >= 2048 * 64) return;
  int s = id >> 6, i = id & 63;
  float freq = powf(10000.0f, -(float)i / 64.0f);
  float ang = (float)s * freq;
  cosb[id] = cosf(ang);
  sinb[id] = sinf(ang);
}

// in-place RoPE on bf16 buffer laid out [rows][128], rows = NH*S
__global__ __launch_bounds__(256) void rope_kernel(u16* __restrict__ p,
                                                   const float* __restrict__ cosb,
                                                   const float* __restrict__ sinb,
                                                   int total) {
  int id = blockIdx.x * 256 + threadIdx.x;   // total = rows*64
  if (id >= total) return;
  int i = id & 63;
  int rs = id >> 6;
  int s = rs & 2047;                          // S = 2048
  size_t base = (size_t)rs * 128;
  float x1 = bf2f(p[base + i]);
  float x2 = bf2f(p[base + i + 64]);
  float c = cosb[s * 64 + i], sn = sinb[s * 64 + i];
  p[base + i]      = f2bf(x1 * c - x2 * sn);
  p[base + i + 64] = f2bf(x2 * c + x1 * sn);
}

// ---------------- bf16 MFMA GEMM: C[m,n] = sum_k A[m,k]*B[n,k] (+bias) ----------------
// mode 0: scatter to Q/K/V bf16 buffers (+bias). mode 1: plain f32 C.
__global__ __launch_bounds__(256) void gemm_bt_kernel(
    const u16* __restrict__ A, const u16* __restrict__ Bw,
    const float* __restrict__ bias,
    float* __restrict__ C, int ldc,
    u16* __restrict__ Qp, u16* __restrict__ Kp, u16* __restrict__ Vp,
    int M, int N, int K, int mode) {
  __shared__ u16 sA[128 * 32];
  __shared__ u16 sB[128 * 32];
  const int t = threadIdx.x;
  const int w = t >> 6, l = t & 63;
  const int wm = (w >> 1) * 64, wn = (w & 1) * 64;
  const int m0 = blockIdx.y * 128, n0 = blockIdx.x * 128;
  const int srow = t >> 2, scol = (t & 3) * 8;

  f32x4 acc[4][4];
#pragma unroll
  for (int i = 0; i < 4; ++i)
#pragma unroll
    for (int j = 0; j < 4; ++j)
#pragma unroll
      for (int r = 0; r < 4; ++r) acc[i][j][r] = 0.0f;

  const size_t arow0 = (size_t)(m0 + srow) * K;
  const size_t arow1 = (size_t)(m0 + 64 + srow) * K;
  const size_t brow0 = (size_t)(n0 + srow) * K;
  const size_t brow1 = (size_t)(n0 + 64 + srow) * K;
#if USE_GLL
  char* ldsA = (char*)sA + (size_t)w * 1024;
  char* ldsB = (char*)sB + (size_t)w * 1024;
#endif

  for (int k0 = 0; k0 < K; k0 += 32) {
#if USE_GLL
    load_lds16(A + arow0 + k0 + scol, ldsA);
    load_lds16(A + arow1 + k0 + scol, ldsA + 4096);
    load_lds16(Bw + brow0 + k0 + scol, ldsB);
    load_lds16(Bw + brow1 + k0 + scol, ldsB + 4096);
#else
    {
      s16x8 a0 = *(const s16x8*)(A + arow0 + k0 + scol);
      s16x8 a1 = *(const s16x8*)(A + arow1 + k0 + scol);
      s16x8 b0 = *(const s16x8*)(Bw + brow0 + k0 + scol);
      s16x8 b1 = *(const s16x8*)(Bw + brow1 + k0 + scol);
      *(s16x8*)&sA[(size_t)srow * 32 + scol] = a0;
      *(s16x8*)&sA[(size_t)(64 + srow) * 32 + scol] = a1;
      *(s16x8*)&sB[(size_t)srow * 32 + scol] = b0;
      *(s16x8*)&sB[(size_t)(64 + srow) * 32 + scol] = b1;
    }
#endif
    __syncthreads();
    s16x8 af[4], bf[4];
#pragma unroll
    for (int m = 0; m < 4; ++m)
      af[m] = *(const s16x8*)&sA[(wm + m * 16 + (l & 15)) * 32 + (l >> 4) * 8];
#pragma unroll
    for (int n = 0; n < 4; ++n)
      bf[n] = *(const s16x8*)&sB[(wn + n * 16 + (l & 15)) * 32 + (l >> 4) * 8];
#pragma unroll
    for (int m = 0; m < 4; ++m)
#pragma unroll
      for (int n = 0; n < 4; ++n)
        acc[m][n] = __builtin_amdgcn_mfma_f32_16x16x32_bf16(af[m], bf[n], acc[m][n], 0, 0, 0);
    __syncthreads();
  }

#pragma unroll
  for (int m = 0; m < 4; ++m) {
#pragma unroll
    for (int n = 0; n < 4; ++n) {
#pragma unroll
      for (int r = 0; r < 4; ++r) {
        int row = m0 + wm + m * 16 + ((l >> 4) << 2) + r;
        int col = n0 + wn + n * 16 + (l & 15);
        float val = acc[m][n][r];
        if (mode == 0) {
          val += bias[col];
          int b = row >> 11, s = row & 2047;
          u16 bvv = f2bf(val);
          if (col < 2048) {
            int h = col >> 7, d = col & 127;
            Qp[(((size_t)(b * 16 + h)) * 2048 + s) * 128 + d] = bvv;
          } else if (col < 2560) {
            int cc = col - 2048; int kh = cc >> 7, d = cc & 127;
            Kp[(((size_t)(b * 4 + kh)) * 2048 + s) * 128 + d] = bvv;
          } else {
            int cc = col - 2560; int kh = cc >> 7, d = cc & 127;
            Vp[(((size_t)(b * 4 + kh)) * 2048 + s) * 128 + d] = bvv;
          }
        } else {
          C[(size_t)row * ldc + col] = val;
        }
      }
    }
  }
}

// ---------------- MFMA flash attention (causal, GQA) ----------------
// Q: [B,16,S,128] bf16 (rope'd), K/V: [B,4,S,128] bf16 (K rope'd)
// O (att): [B,S,2048] bf16.  grid = (B*16, S/64), block = 256 (4 waves).
// Wave w owns q-rows [q0+w*16, q0+w*16+16). KV tile = 32 rows.
// Fragment layouts (HW-verified via gemm_bt): A/B row(col)=l&15, k=(l>>4)*8+e;
// C/D col=l&15, row=(l>>4)*4+r.
__global__ __launch_bounds__(256) void flash_mfma_kernel(const u16* __restrict__ Q,
                                                         const u16* __restrict__ Kb,
                                                         const u16* __restrict__ Vb,
                                                         u16* __restrict__ O) {
  const int S = 2048;
  __shared__ u16 sK[32 * 128];    // XOR-swizzled rows: idx ^= (j&7)<<3
  __shared__ u16 sVt[128 * 40];   // V^T, stride 40 (80B -> bank stride 20)
  __shared__ u16 sP[4 * 16 * 40]; // per-wave P slabs, stride 40

  const int t = threadIdx.x, w = t >> 6, l = t & 63;
  const int lg = l >> 4, lr = l & 15;
  const int bh = blockIdx.x, b = bh >> 4, h = bh & 15, kvh = h >> 2;
  const int q0 = blockIdx.y * 64;

  const u16* qbase = Q + (((size_t)(b * 16 + h)) * S + q0 + w * 16) * 128;
  const u16* kbase = Kb + ((size_t)(b * 4 + kvh)) * S * 128;
  const u16* vbase = Vb + ((size_t)(b * 4 + kvh)) * S * 128;

  // Q fragments in registers: qa[kc][e] = Q[q=lr][d = kc*32 + lg*8 + e]
  s16x8 qa[4];
#pragma unroll
  for (int kc = 0; kc < 4; ++kc)
    qa[kc] = *(const s16x8*)&qbase[(size_t)lr * 128 + kc * 32 + lg * 8];

  f32x4 o[8];
#pragma unroll
  for (int dt = 0; dt < 8; ++dt)
#pragma unroll
    for (int r = 0; r < 4; ++r) o[dt][r] = 0.0f;
  float mrun[4], lrun[4];
#pragma unroll
  for (int r = 0; r < 4; ++r) { mrun[r] = -1e30f; lrun[r] = 0.0f; }

  u16* sPw = &sP[w * 16 * 40];
  const float SCALE = 0.08838834764831845f;
  const int nt = q0 / 32 + 2;

  for (int kt = 0; kt < nt; ++kt) {
    __syncthreads();   // prior tile's sK/sVt readers done
    // stage K (swizzled), coalesced global reads
#pragma unroll
    for (int i = 0; i < 2; ++i) {
      int cid = t + i * 256;
      int j = cid >> 4, c = cid & 15;
      s16x8 kk = *(const s16x8*)&kbase[((size_t)(kt * 32 + j)) * 128 + c * 8];
      *(s16x8*)&sK[(j * 128 + c * 8) ^ ((j & 7) << 3)] = kk;
    }
    // stage V^T (global reads strided by row; V is L2/L3-resident)
#pragma unroll
    for (int i = 0; i < 2; ++i) {
      int cid = t + i * 256;
      int j = cid & 31, d0 = (cid >> 5) * 8;
      s16x8 vv = *(const s16x8*)&vbase[((size_t)(kt * 32 + j)) * 128 + d0];
#pragma unroll
      for (int e = 0; e < 8; ++e) sVt[(d0 + e) * 40 + j] = (u16)vv[e];
    }
    __syncthreads();   // staging visible

    // QK^T: sc[n] covers j = n*16 + lr
    f32x4 sc[2];
#pragma unroll
    for (int n = 0; n < 2; ++n) {
#pragma unroll
      for (int r = 0; r < 4; ++r) sc[n][r] = 0.0f;
      int j = n * 16 + lr;
#pragma unroll
      for (int kc = 0; kc < 4; ++kc) {
        s16x8 kf = *(const s16x8*)&sK[(j * 128 + kc * 32 + lg * 8) ^ ((j & 7) << 3)];
        sc[n] = __builtin_amdgcn_mfma_f32_16x16x32_bf16(qa[kc], kf, sc[n], 0, 0, 0);
      }
    }

    // online softmax per output row r (row lives in one 16-lane group)
#pragma unroll
    for (int r = 0; r < 4; ++r) {
      int qi = q0 + w * 16 + lg * 4 + r;
      float s0 = (kt * 32 + lr <= qi) ? sc[0][r] * SCALE : -1e30f;
      float s1 = (kt * 32 + 16 + lr <= qi) ? sc[1][r] * SCALE : -1e30f;
      float mt = fmaxf(s0, s1);
#pragma unroll
      for (int off = 1; off < 16; off <<= 1) mt = fmaxf(mt, __shfl_xor(mt, off));
      float mnew = fmaxf(mrun[r], mt);
      float p0 = __expf(s0 - mnew);
      float p1 = __expf(s1 - mnew);
      float corr = __expf(mrun[r] - mnew);
      float ps = p0 + p1;
#pragma unroll
      for (int off = 1; off < 16; off <<= 1) ps += __shfl_xor(ps, off);
      lrun[r] = lrun[r] * corr + ps;
      mrun[r] = mnew;
#pragma unroll
      for (int dt = 0; dt < 8; ++dt) o[dt][r] *= corr;
      sPw[(lg * 4 + r) * 40 + lr]      = f2bf(p0);
      sPw[(lg * 4 + r) * 40 + 16 + lr] = f2bf(p1);
    }
    __syncthreads();   // P visible (also keeps waves phase-locked)

    // PV: one K=32 MFMA per 16-wide d-tile
    s16x8 pa = *(const s16x8*)&sPw[lr * 40 + lg * 8];
#pragma unroll
    for (int dt = 0; dt < 8; ++dt) {
      s16x8 vt = *(const s16x8*)&sVt[(dt * 16 + lr) * 40 + lg * 8];
      o[dt] = __builtin_amdgcn_mfma_f32_16x16x32_bf16(pa, vt, o[dt], 0, 0, 0);
    }
  }

  // epilogue: normalize and store
#pragma unroll
  for (int r = 0; r < 4; ++r) {
    float inv = 1.0f / lrun[r];
    int qi = q0 + w * 16 + lg * 4 + r;
    size_t base = ((size_t)b * S + qi) * 2048 + h * 128;
#pragma unroll
    for (int dt = 0; dt < 8; ++dt)
      O[base + dt * 16 + lr] = f2bf(o[dt][r] * inv);
  }
}

// ---------------- launch ----------------

extern "C" void kernel_launch(void* const* d_in, const int* in_sizes, int n_in,
                              void* d_out, int out_size, void* d_ws, size_t ws_size,
                              hipStream_t stream) {
  const float* x  = (const float*)d_in[0];
  const float* wq = (const float*)d_in[1];
  const float* bq = (const float*)d_in[2];
  const float* wk = (const float*)d_in[3];
  const float* bk = (const float*)d_in[4];
  const float* wv = (const float*)d_in[5];
  const float* bv = (const float*)d_in[6];
  const float* wo = (const float*)d_in[7];
  float* out = (float*)d_out;

  char* ws = (char*)d_ws;
  u16* xb    = (u16*)ws;    ws += (size_t)4096 * 2048 * 2;
  u16* wqkv  = (u16*)ws;    ws += (size_t)3072 * 2048 * 2;
  float* bqkv = (float*)ws; ws += (size_t)3072 * 4;
  u16* wob   = (u16*)ws;    ws += (size_t)2048 * 2048 * 2;
  u16* Qb    = (u16*)ws;    ws += (size_t)32 * 2048 * 128 * 2;
  u16* Kbuf  = (u16*)ws;    ws += (size_t)8 * 2048 * 128 * 2;
  u16* Vbuf  = (u16*)ws;    ws += (size_t)8 * 2048 * 128 * 2;
  float* cosb = (float*)ws; ws += (size_t)2048 * 64 * 4;
  float* sinb = (float*)ws; ws += (size_t)2048 * 64 * 4;
  u16* att   = (u16*)ws;    ws += (size_t)4096 * 2048 * 2;

  cast_bf16_kernel<<<8192, 256, 0, stream>>>(x, xb, 4096 * 2048 / 4);
  pack_qkv_w_kernel<<<6144, 256, 0, stream>>>(wq, wk, wv, wqkv);
  pack_bias_kernel<<<12, 256, 0, stream>>>(bq, bk, bv, bqkv);
  cast_bf16_kernel<<<4096, 256, 0, stream>>>(wo, wob, 2048 * 2048 / 4);
  rope_table_kernel<<<512, 256, 0, stream>>>(cosb, sinb);

  gemm_bt_kernel<<<dim3(24, 32), 256, 0, stream>>>(xb, wqkv, bqkv, nullptr, 0,
                                                   Qb, Kbuf, Vbuf, 4096, 3072, 2048, 0);
  rope_kernel<<<16384, 256, 0, stream>>>(Qb, cosb, sinb, 32 * 2048 * 64);
  rope_kernel<<<4096, 256, 0, stream>>>(Kbuf, cosb, sinb, 8 * 2048 * 64);

  flash_mfma_kernel<<<dim3(32, 32), 256, 0, stream>>>(Qb, Kbuf, Vbuf, att);

  gemm_bt_kernel<<<dim3(16, 32), 256, 0, stream>>>(att, wob, nullptr, out, 2048,
                                                   nullptr, nullptr, nullptr, 4096, 2048, 2048, 1);
}